// Round 4
// baseline (483.606 us; speedup 1.0000x reference)
//
#include <hip/hip_runtime.h>
#include <stdint.h>

#define T_ 2048
#define H_ 16

typedef __attribute__((ext_vector_type(8))) short bf16x8;
typedef __attribute__((ext_vector_type(4))) float f32x4;

__device__ __forceinline__ unsigned short f2bf(float x){
  union { float f; uint32_t u; } v; v.f = x;
  uint32_t r = v.u + 0x7FFFu + ((v.u >> 16) & 1u);
  return (unsigned short)(r >> 16);
}

__device__ __forceinline__ void g2l16(const void* g, void* l){
  __builtin_amdgcn_global_load_lds(
      (const __attribute__((address_space(1))) void*)g,
      (__attribute__((address_space(3))) void*)l, 16, 0, 0);
}

// ---------------- fused prep: cvt3 (blocks 0..24575) + wt (24576..25599) +
// pack_mask (25600..27647) ----------------
__global__ __launch_bounds__(256) void prep_kernel(
    const float* __restrict__ q, const float* __restrict__ k, const float* __restrict__ v,
    unsigned short* __restrict__ oq, unsigned short* __restrict__ ok, unsigned short* __restrict__ ov,
    const float* __restrict__ W0, const float* __restrict__ W1,
    const float* __restrict__ W2, const float* __restrict__ W3,
    unsigned short* __restrict__ wt_out,
    const int* __restrict__ mask, unsigned long long* __restrict__ mw){
  __shared__ unsigned short t[64][72];
  int bx = blockIdx.x;
  int tid = threadIdx.x;
  if (bx < 24576){
    // fp32 -> bf16 convert of q,k,v
    const long NG = (long)8*1024*1024/4;
    long g = (long)bx*256 + tid;
    const float* s; unsigned short* d;
    if (g < NG){ s=q; d=oq; }
    else if (g < 2*NG){ s=k; d=ok; g-=NG; }
    else { s=v; d=ov; g-=2*NG; }
    long i = g*4;
    float4 val = *(const float4*)(s+i);
    ushort4 r;
    r.x=f2bf(val.x); r.y=f2bf(val.y); r.z=f2bf(val.z); r.w=f2bf(val.w);
    *(ushort4*)(d+i) = r;
  } else if (bx < 25600){
    // W (KxN f32) -> Wt (NxK bf16); Wq pre-scaled by log2(e)
    int wb = bx - 24576;
    int z = wb >> 8, rem = wb & 255;
    const float* W = (z==0)?W0:(z==1)?W1:(z==2)?W2:W3;
    const float sc = (z==0) ? 1.44269504f : 1.0f;
    unsigned short* o = wt_out + (size_t)z*1024*1024;
    int k0 = (rem&15)*64, n0 = (rem>>4)*64;
    int i = tid>>2, cs = (tid&3)*16;
    const float* src = W + (size_t)(k0+i)*1024 + n0 + cs;
    #pragma unroll
    for (int c=0;c<16;c+=4){
      float4 vv = *(const float4*)(src + c);
      t[i][cs+c+0]=f2bf(vv.x*sc); t[i][cs+c+1]=f2bf(vv.y*sc);
      t[i][cs+c+2]=f2bf(vv.z*sc); t[i][cs+c+3]=f2bf(vv.w*sc);
    }
    __syncthreads();
    int j = tid>>2; int ks = (tid&3)*16;
    __align__(16) unsigned short buf[16];
    #pragma unroll
    for (int c=0;c<16;c++) buf[c] = t[ks+c][j];
    unsigned short* dst = o + (size_t)(n0+j)*1024 + k0 + ks;
    *(uint4*)dst = *(const uint4*)(buf);
    *(uint4*)(dst+8) = *(const uint4*)(buf+8);
  } else {
    // mask int32 -> bitpacked u64
    int pb = bx - 25600;
    int wid = tid>>6, lane = tid&63;
    long r = (long)pb*4 + wid;
    const int* mrow = mask + r*2048;
    unsigned long long* orow = mw + r*32;
    for (int kk=0; kk<32; kk++){
      int vv = mrow[kk*64 + lane];
      unsigned long long bal = __ballot(vv != 0);
      if (lane==0) orow[kk] = bal;
    }
  }
}

// ---------------- shared 128x128-tile NT GEMM body ----------------
// XOR-swizzled LDS granules: granule (row m, chunk c of 8) holds global chunk c^(m&7).
template<int FUSED>
__device__ __forceinline__ void gemm_body(
    const unsigned short* __restrict__ A,
    const unsigned short* __restrict__ Bt,
    const float* __restrict__ bias, float bscale,
    const float* __restrict__ resid,
    void* __restrict__ Cout,
    unsigned short* sA, unsigned short* sB){
  const int K = 1024;
  int tid = threadIdx.x;
  int wid = tid>>6, lane = tid&63;
  int ln = lane&15, qd = lane>>4;
  int wr = wid>>1, wc = wid&1;
  long m0 = (long)blockIdx.y*128;
  long n0 = (long)blockIdx.x*128;
  f32x4 acc[4][4] = {};
  for (int k0=0; k0<K; k0+=64){
    __syncthreads();
    #pragma unroll
    for (int s=0;s<4;s++){
      int G = s*256 + tid;
      int mm = G>>3, cc = G&7;
      g2l16(A  + (m0+mm)*(long)K + k0 + ((cc^(mm&7))<<3),
            (char*)sA + (size_t)G*16);
      g2l16(Bt + (n0+mm)*(long)K + k0 + ((cc^(mm&7))<<3),
            (char*)sB + (size_t)G*16);
    }
    __syncthreads();
    #pragma unroll
    for (int ks=0;ks<2;ks++){
      bf16x8 af[4], bfv[4];
      #pragma unroll
      for (int i=0;i<4;i++){
        int rowa = wr*64 + i*16 + ln;
        af[i]  = *(const bf16x8*)(sA + rowa*64 + (((ks*4+qd)^(rowa&7))<<3));
        int rowb = wc*64 + i*16 + ln;
        bfv[i] = *(const bf16x8*)(sB + rowb*64 + (((ks*4+qd)^(rowb&7))<<3));
      }
      #pragma unroll
      for (int i=0;i<4;i++)
        #pragma unroll
        for (int j=0;j<4;j++)
          acc[i][j] = __builtin_amdgcn_mfma_f32_16x16x32_bf16(af[i], bfv[j], acc[i][j], 0,0,0);
    }
  }
  long gm0 = m0 + wr*64, gn0 = n0 + wc*64;
  #pragma unroll
  for (int j=0;j<4;j++){
    long gn = gn0 + j*16 + ln;
    float bv = bias[gn]*bscale;
    #pragma unroll
    for (int i=0;i<4;i++){
      long gm = gm0 + i*16 + qd*4;
      #pragma unroll
      for (int r=0;r<4;r++){
        float val = acc[i][j][r] + bv;
        if (FUSED){
          ((float*)Cout)[(gm+r)*1024 + gn] = val + resid[(gm+r)*1024 + gn];
        } else {
          ((unsigned short*)Cout)[(gm+r)*1024 + gn] = f2bf(val);
        }
      }
    }
  }
}

// merged QKV projection: grid (8, 64, 3)
__global__ __launch_bounds__(256,2) void gemm_qkv(
    const unsigned short* __restrict__ Aq, const unsigned short* __restrict__ Ak,
    const unsigned short* __restrict__ Av, const unsigned short* __restrict__ Wt,
    const float* __restrict__ bq, const float* __restrict__ bk, const float* __restrict__ bv,
    unsigned short* __restrict__ Cq, unsigned short* __restrict__ Ck,
    unsigned short* __restrict__ Cv){
  __shared__ unsigned short sA[128*64];
  __shared__ unsigned short sB[128*64];
  int z = blockIdx.z;
  const unsigned short* A  = (z==0)?Aq:(z==1)?Ak:Av;
  const unsigned short* Bt = Wt + (size_t)z*1024*1024;
  const float* bias        = (z==0)?bq:(z==1)?bk:bv;
  unsigned short* C        = (z==0)?Cq:(z==1)?Ck:Cv;
  float bscale             = (z==0)?1.44269504f:1.0f;
  gemm_body<0>(A, Bt, bias, bscale, nullptr, C, sA, sB);
}

// output projection + bias + residual (f32 out)
__global__ __launch_bounds__(256,2) void gemm_out(
    const unsigned short* __restrict__ A, const unsigned short* __restrict__ Bt,
    const float* __restrict__ bias, const float* __restrict__ resid,
    float* __restrict__ Cout){
  __shared__ unsigned short sA[128*64];
  __shared__ unsigned short sB[128*64];
  gemm_body<1>(A, Bt, bias, 1.0f, resid, Cout, sA, sB);
}

// ---------------- vh (B*T, H*64) -> vt[(b*H+h)*64+dv][t], PERMUTED columns ----
// Column t0+p holds V[t0 + k(p)] with k(p) = (p&3)*16 + (p>>2) per 64-block,
// matching the position order attention's P-tile is written in.
__global__ __launch_bounds__(256) void vt_kernel(
    const unsigned short* __restrict__ vh, unsigned short* __restrict__ vt){
  __shared__ unsigned short t[64][72];
  int t0 = blockIdx.x*64;
  int bh = blockIdx.y;
  int b = bh>>4, h = bh&15;
  int tid = threadIdx.x;
  int i = tid>>2, cs=(tid&3)*16;
  const unsigned short* src = vh + ((long)b*T_ + t0 + i)*1024 + h*64 + cs;
  *(bf16x8*)&t[i][cs]   = *(const bf16x8*)(src);
  *(bf16x8*)&t[i][cs+8] = *(const bf16x8*)(src+8);
  __syncthreads();
  int j = tid>>2; int ks=(tid&3)*16;
  __align__(16) unsigned short buf[16];
  #pragma unroll
  for (int c=0;c<16;c++){
    int p = ks + c;
    int keyloc = (p&3)*16 + (p>>2);
    buf[c] = t[keyloc][j];
  }
  unsigned short* dst = vt + ((long)bh*64 + j)*2048 + t0 + ks;
  *(uint4*)dst = *(const uint4*)buf;
  *(uint4*)(dst+8) = *(const uint4*)(buf+8);
}

// ---------------- per-tile K/V staging for attention ----------------
__device__ __forceinline__ void attn_stage(
    const unsigned short* khB, const unsigned short* vtB2, int t,
    unsigned short* kSb, unsigned short* vSb, int tid){
  #pragma unroll
  for (int s=0;s<4;s++){
    int G = s*128 + tid;
    int ii = G>>3, cc = G&7;
    g2l16(khB  + ((long)(t*64+ii))*1024 + ((cc^(ii&7))<<3), (char*)kSb + (size_t)G*16);
    g2l16(vtB2 + (long)ii*2048 + t*64   + ((cc^(ii&7))<<3), (char*)vSb + (size_t)G*16);
  }
}

// ---------------- flash attention v4: software-pipelined staging ----------------
// 128 threads = 2 waves, each wave owns 64 q-rows. Double-buffered K/V staging;
// one raw barrier per tile; the vmcnt(0) drain only waits on loads issued a
// full tile earlier (latency hidden). Softmax: exp2 of raw log2-unit scores
// (-20 pre-shift in MFMA C-init), truncate-pack via v_perm, multiplicative
// bitmask AND on packed pairs (exact zeros). Row sums via ones-MFMA.
__global__ __launch_bounds__(128,2) void attn_kernel(
    const unsigned short* __restrict__ qh,
    const unsigned short* __restrict__ kh,
    const unsigned short* __restrict__ vt,
    const unsigned long long* __restrict__ mw,
    unsigned short* __restrict__ aout){
  __shared__ unsigned short kS[2][64*64];
  __shared__ unsigned short vS[2][64*64];
  __shared__ unsigned short pS[2][64][72];
  int tid=threadIdx.x, wid=tid>>6, lane=tid&63;
  int ln=lane&15, qd=lane>>4;
  int q0 = blockIdx.x*128;
  int bh = blockIdx.y, b = bh>>4, h = bh&15;
  int wq0 = q0 + wid*64;

  // Q A-fragments for 4 row-groups x 2 ksteps
  bf16x8 qf[4][2];
  const unsigned short* qbase = qh + ((long)b*T_ + wq0)*1024 + h*64 + qd*8;
  #pragma unroll
  for (int rg=0;rg<4;rg++){
    qf[rg][0] = *(const bf16x8*)(qbase + (size_t)(rg*16+ln)*1024);
    qf[rg][1] = *(const bf16x8*)(qbase + (size_t)(rg*16+ln)*1024 + 32);
  }
  f32x4 oacc[4][4] = {};
  f32x4 lsum[4] = {};
  bf16x8 ones;
  #pragma unroll
  for (int i=0;i<8;i++) ones[i] = (short)0x3F80;

  const unsigned short* khB  = kh + ((long)b*T_)*1024 + h*64;
  const unsigned short* vtB2 = vt + ((long)bh*64)*2048;
  const unsigned long long* mwB = mw + ((long)(b*T_ + wq0 + qd*4))*32;

  // prologue: stage tile 0 into buffer 0
  attn_stage(khB, vtB2, 0, kS[0], vS[0], tid);

  for (int t=0; t<32; t++){
    int buf = t & 1;
    // wait for tile t's staging (issued one tile ago) + raw barrier
    asm volatile("s_waitcnt vmcnt(0) lgkmcnt(0)\n\ts_barrier" ::: "memory");
    // prefetch tile t+1 into the other buffer
    if (t < 31)
      attn_stage(khB, vtB2, t+1, kS[buf^1], vS[buf^1], tid);
    // mask words for tile t (L2-resident; consumed after QK MFMAs)
    unsigned long long mb[4][4];
    #pragma unroll
    for (int rg=0;rg<4;rg++)
      #pragma unroll
      for (int r=0;r<4;r++)
        mb[rg][r] = mwB[(size_t)(rg*16+r)*32 + t];

    const unsigned short* kSb = kS[buf];
    const unsigned short* vSb = vS[buf];

    // K B-frags (shared across row-groups)
    bf16x8 kb[2][4];
    #pragma unroll
    for (int ks=0;ks<2;ks++)
      #pragma unroll
      for (int nt=0;nt<4;nt++){
        int row = nt*16+ln;
        kb[ks][nt] = *(const bf16x8*)(kSb + row*64 + (((ks*4+qd)^(row&7))<<3));
      }
    #pragma unroll
    for (int rg=0;rg<4;rg++){
      f32x4 sa[4];
      #pragma unroll
      for (int nt=0;nt<4;nt++){
        f32x4 z = {-20.f,-20.f,-20.f,-20.f};
        z = __builtin_amdgcn_mfma_f32_16x16x32_bf16(qf[rg][0], kb[0][nt], z, 0,0,0);
        z = __builtin_amdgcn_mfma_f32_16x16x32_bf16(qf[rg][1], kb[1][nt], z, 0,0,0);
        sa[nt]=z;
      }
      #pragma unroll
      for (int r=0;r<4;r++){
        unsigned long long w = mb[rg][r] >> ln;   // bit nt*16 = key nt*16+ln
        unsigned int lo = (unsigned int)w, hi = (unsigned int)(w>>32);
        float p0 = __builtin_amdgcn_exp2f(sa[0][r]);
        float p1 = __builtin_amdgcn_exp2f(sa[1][r]);
        float p2 = __builtin_amdgcn_exp2f(sa[2][r]);
        float p3 = __builtin_amdgcn_exp2f(sa[3][r]);
        // truncate-pack bf16 pairs, then multiplicative bitmask (exact zeros)
        unsigned loP = __builtin_amdgcn_perm(__float_as_uint(p1), __float_as_uint(p0), 0x07060302u);
        unsigned hiP = __builtin_amdgcn_perm(__float_as_uint(p3), __float_as_uint(p2), 0x07060302u);
        loP &= (lo & 0x00010001u) * 0xFFFFu;
        hiP &= (hi & 0x00010001u) * 0xFFFFu;
        *(unsigned long long*)&pS[wid][rg*16+qd*4+r][ln*4] =
            ((unsigned long long)hiP<<32) | (unsigned long long)loP;
      }
    }
    asm volatile("s_waitcnt lgkmcnt(0)" ::: "memory");

    // O += P * V (position space; vS columns carry matching permutation)
    #pragma unroll
    for (int c=0;c<2;c++){
      bf16x8 vb[4];
      #pragma unroll
      for (int d=0;d<4;d++){
        int row = d*16+ln;
        vb[d] = *(const bf16x8*)(vSb + row*64 + (((c*4+qd)^(row&7))<<3));
      }
      #pragma unroll
      for (int rg=0;rg<4;rg++){
        bf16x8 pa = *(const bf16x8*)&pS[wid][rg*16+ln][c*32+qd*8];
        #pragma unroll
        for (int d=0;d<4;d++)
          oacc[rg][d] = __builtin_amdgcn_mfma_f32_16x16x32_bf16(pa, vb[d], oacc[rg][d], 0,0,0);
        lsum[rg] = __builtin_amdgcn_mfma_f32_16x16x32_bf16(pa, ones, lsum[rg], 0,0,0);
      }
    }
  }

  // epilogue: normalize and store (lsum rows match oacc rows lane-for-lane)
  #pragma unroll
  for (int rg=0;rg<4;rg++){
    float linv[4];
    #pragma unroll
    for (int r=0;r<4;r++) linv[r] = (lsum[rg][r]>0.f)?(1.f/lsum[rg][r]):0.f;
    long rowb = (long)b*T_ + wq0 + rg*16 + qd*4;
    #pragma unroll
    for (int d=0;d<4;d++)
      #pragma unroll
      for (int r=0;r<4;r++)
        aout[(rowb+r)*1024 + h*64 + d*16 + ln] = f2bf(oacc[rg][d][r]*linv[r]);
  }
}

// ---------------- LayerNorm over D=1024 ----------------
__global__ __launch_bounds__(256) void ln_kernel(const float* __restrict__ x,
    const float* __restrict__ gamma, const float* __restrict__ beta, float* __restrict__ out){
  __shared__ float red[8];
  long row = blockIdx.x;
  const float* xr = x + row*1024;
  int tid = threadIdx.x;
  float4 v = *(const float4*)(xr + tid*4);
  float s = v.x+v.y+v.z+v.w;
  float sq = v.x*v.x+v.y*v.y+v.z*v.z+v.w*v.w;
  #pragma unroll
  for (int off=1; off<64; off<<=1){
    s  += __shfl_xor(s,off,64);
    sq += __shfl_xor(sq,off,64);
  }
  int wid=tid>>6, lane=tid&63;
  if (lane==0){ red[wid]=s; red[4+wid]=sq; }
  __syncthreads();
  float S  = red[0]+red[1]+red[2]+red[3];
  float SQ = red[4]+red[5]+red[6]+red[7];
  float mu = S*(1.0f/1024.0f);
  float var = SQ*(1.0f/1024.0f) - mu*mu;
  float rstd = rsqrtf(var + 1e-5f);
  float4 g  = *(const float4*)(gamma + tid*4);
  float4 be = *(const float4*)(beta + tid*4);
  float4 o;
  o.x=(v.x-mu)*rstd*g.x+be.x;
  o.y=(v.y-mu)*rstd*g.y+be.y;
  o.z=(v.z-mu)*rstd*g.z+be.z;
  o.w=(v.w-mu)*rstd*g.w+be.w;
  *(float4*)(out + row*1024 + tid*4) = o;
}

extern "C" void kernel_launch(void* const* d_in, const int* in_sizes, int n_in,
                              void* d_out, int out_size, void* d_ws, size_t ws_size,
                              hipStream_t stream){
  const float* q = (const float*)d_in[0];
  const float* k = (const float*)d_in[1];
  const float* v = (const float*)d_in[2];
  const int*   mask = (const int*)d_in[3];
  const float* Wq = (const float*)d_in[4];
  const float* bq = (const float*)d_in[5];
  const float* Wk = (const float*)d_in[6];
  const float* bk = (const float*)d_in[7];
  const float* Wv = (const float*)d_in[8];
  const float* bv = (const float*)d_in[9];
  const float* Wo = (const float*)d_in[10];
  const float* bo = (const float*)d_in[11];
  const float* gamma = (const float*)d_in[12];
  const float* beta  = (const float*)d_in[13];
  float* out = (float*)d_out;
  char* ws = (char*)d_ws;
  const size_t MB = 1024*1024;
  // workspace (106 MiB):
  //  0- 8  Wt          8-10 mw          10-26 qhB   26-42 khB   42-58 vhB
  // 58-74  qbf(->aout) 74-90 kbf        90-106 vbf(->vtB)
  // xbuf = 10-42 (32 MiB over qhB+khB, both dead by out-proj)
  unsigned short*     Wt  = (unsigned short*)(ws + 0);
  unsigned long long* mw  = (unsigned long long*)(ws + 8*MB);
  unsigned short*     qhB = (unsigned short*)(ws + 10*MB);
  unsigned short*     khB = (unsigned short*)(ws + 26*MB);
  unsigned short*     vhB = (unsigned short*)(ws + 42*MB);
  unsigned short*     qbf = (unsigned short*)(ws + 58*MB);
  unsigned short*     kbf = (unsigned short*)(ws + 74*MB);
  unsigned short*     vbf = (unsigned short*)(ws + 90*MB);
  unsigned short*     vtB  = vbf;   // alias: vbf dead after QKV GEMM
  unsigned short*     aout = qbf;   // alias: qbf dead after QKV GEMM
  float*              xbuf = (float*)(ws + 10*MB);

  prep_kernel<<<27648,256,0,stream>>>(q,k,v,qbf,kbf,vbf, Wq,Wk,Wv,Wo, Wt, mask, mw);
  gemm_qkv<<<dim3(8,64,3),256,0,stream>>>(qbf,kbf,vbf, Wt, bq,bk,bv, qhB,khB,vhB);
  vt_kernel<<<dim3(32,64),256,0,stream>>>(vhB, vtB);
  attn_kernel<<<dim3(16,64),128,0,stream>>>(qhB, khB, vtB, mw, aout);
  gemm_out<<<dim3(8,64),256,0,stream>>>(aout, Wt+3*1024*1024, bo, q, xbuf);
  ln_kernel<<<8192,256,0,stream>>>(xbuf, gamma, beta, out);
}

// Round 5
// 467.777 us; speedup vs baseline: 1.0338x; 1.0338x over previous
//
#include <hip/hip_runtime.h>
#include <stdint.h>

#define T_ 2048
#define H_ 16

typedef __attribute__((ext_vector_type(8))) short bf16x8;
typedef __attribute__((ext_vector_type(4))) float f32x4;

__device__ __forceinline__ unsigned short f2bf(float x){
  union { float f; uint32_t u; } v; v.f = x;
  uint32_t r = v.u + 0x7FFFu + ((v.u >> 16) & 1u);
  return (unsigned short)(r >> 16);
}

__device__ __forceinline__ void g2l16(const void* g, void* l){
  __builtin_amdgcn_global_load_lds(
      (const __attribute__((address_space(1))) void*)g,
      (__attribute__((address_space(3))) void*)l, 16, 0, 0);
}

// ---------------- fused prep: cvt3 (blocks 0..24575) + wt (24576..25599) +
// pack_mask (25600..27647) ----------------
// Mask is packed TRANSPOSED: mwT[(b*32 + key_word)*2048 + q_row], so one
// (q-block, key-tile) needs a contiguous 1 KiB run -> stageable by g2l16.
__global__ __launch_bounds__(256) void prep_kernel(
    const float* __restrict__ q, const float* __restrict__ k, const float* __restrict__ v,
    unsigned short* __restrict__ oq, unsigned short* __restrict__ ok, unsigned short* __restrict__ ov,
    const float* __restrict__ W0, const float* __restrict__ W1,
    const float* __restrict__ W2, const float* __restrict__ W3,
    unsigned short* __restrict__ wt_out,
    const int* __restrict__ mask, unsigned long long* __restrict__ mw){
  __shared__ unsigned short t[64][72];
  int bx = blockIdx.x;
  int tid = threadIdx.x;
  if (bx < 24576){
    // fp32 -> bf16 convert of q,k,v
    const long NG = (long)8*1024*1024/4;
    long g = (long)bx*256 + tid;
    const float* s; unsigned short* d;
    if (g < NG){ s=q; d=oq; }
    else if (g < 2*NG){ s=k; d=ok; g-=NG; }
    else { s=v; d=ov; g-=2*NG; }
    long i = g*4;
    float4 val = *(const float4*)(s+i);
    ushort4 r;
    r.x=f2bf(val.x); r.y=f2bf(val.y); r.z=f2bf(val.z); r.w=f2bf(val.w);
    *(ushort4*)(d+i) = r;
  } else if (bx < 25600){
    // W (KxN f32) -> Wt (NxK bf16); Wq pre-scaled by log2(e)
    int wb = bx - 24576;
    int z = wb >> 8, rem = wb & 255;
    const float* W = (z==0)?W0:(z==1)?W1:(z==2)?W2:W3;
    const float sc = (z==0) ? 1.44269504f : 1.0f;
    unsigned short* o = wt_out + (size_t)z*1024*1024;
    int k0 = (rem&15)*64, n0 = (rem>>4)*64;
    int i = tid>>2, cs = (tid&3)*16;
    const float* src = W + (size_t)(k0+i)*1024 + n0 + cs;
    #pragma unroll
    for (int c=0;c<16;c+=4){
      float4 vv = *(const float4*)(src + c);
      t[i][cs+c+0]=f2bf(vv.x*sc); t[i][cs+c+1]=f2bf(vv.y*sc);
      t[i][cs+c+2]=f2bf(vv.z*sc); t[i][cs+c+3]=f2bf(vv.w*sc);
    }
    __syncthreads();
    int j = tid>>2; int ks = (tid&3)*16;
    __align__(16) unsigned short buf[16];
    #pragma unroll
    for (int c=0;c<16;c++) buf[c] = t[ks+c][j];
    unsigned short* dst = o + (size_t)(n0+j)*1024 + k0 + ks;
    *(uint4*)dst = *(const uint4*)(buf);
    *(uint4*)(dst+8) = *(const uint4*)(buf+8);
  } else {
    // mask int32 -> bitpacked u64, transposed layout
    int pb = bx - 25600;
    int wid = tid>>6, lane = tid&63;
    long r = (long)pb*4 + wid;          // global row in B*T
    int b  = (int)(r >> 11);
    int tr = (int)(r & 2047);
    const int* mrow = mask + r*2048;
    for (int kk=0; kk<32; kk++){
      int vv = mrow[kk*64 + lane];
      unsigned long long bal = __ballot(vv != 0);
      if (lane==0) mw[((size_t)(b*32+kk))*2048 + tr] = bal;
    }
  }
}

// ---------------- shared 128x128-tile NT GEMM body ----------------
// XOR-swizzled LDS granules: granule (row m, chunk c of 8) holds global chunk c^(m&7).
template<int FUSED>
__device__ __forceinline__ void gemm_body(
    const unsigned short* __restrict__ A,
    const unsigned short* __restrict__ Bt,
    const float* __restrict__ bias, float bscale,
    const float* __restrict__ resid,
    void* __restrict__ Cout,
    unsigned short* sA, unsigned short* sB){
  const int K = 1024;
  int tid = threadIdx.x;
  int wid = tid>>6, lane = tid&63;
  int ln = lane&15, qd = lane>>4;
  int wr = wid>>1, wc = wid&1;
  long m0 = (long)blockIdx.y*128;
  long n0 = (long)blockIdx.x*128;
  f32x4 acc[4][4] = {};
  for (int k0=0; k0<K; k0+=64){
    __syncthreads();
    #pragma unroll
    for (int s=0;s<4;s++){
      int G = s*256 + tid;
      int mm = G>>3, cc = G&7;
      g2l16(A  + (m0+mm)*(long)K + k0 + ((cc^(mm&7))<<3),
            (char*)sA + (size_t)G*16);
      g2l16(Bt + (n0+mm)*(long)K + k0 + ((cc^(mm&7))<<3),
            (char*)sB + (size_t)G*16);
    }
    __syncthreads();
    #pragma unroll
    for (int ks=0;ks<2;ks++){
      bf16x8 af[4], bfv[4];
      #pragma unroll
      for (int i=0;i<4;i++){
        int rowa = wr*64 + i*16 + ln;
        af[i]  = *(const bf16x8*)(sA + rowa*64 + (((ks*4+qd)^(rowa&7))<<3));
        int rowb = wc*64 + i*16 + ln;
        bfv[i] = *(const bf16x8*)(sB + rowb*64 + (((ks*4+qd)^(rowb&7))<<3));
      }
      #pragma unroll
      for (int i=0;i<4;i++)
        #pragma unroll
        for (int j=0;j<4;j++)
          acc[i][j] = __builtin_amdgcn_mfma_f32_16x16x32_bf16(af[i], bfv[j], acc[i][j], 0,0,0);
    }
  }
  long gm0 = m0 + wr*64, gn0 = n0 + wc*64;
  #pragma unroll
  for (int j=0;j<4;j++){
    long gn = gn0 + j*16 + ln;
    float bv = bias[gn]*bscale;
    #pragma unroll
    for (int i=0;i<4;i++){
      long gm = gm0 + i*16 + qd*4;
      #pragma unroll
      for (int r=0;r<4;r++){
        float val = acc[i][j][r] + bv;
        if (FUSED){
          ((float*)Cout)[(gm+r)*1024 + gn] = val + resid[(gm+r)*1024 + gn];
        } else {
          ((unsigned short*)Cout)[(gm+r)*1024 + gn] = f2bf(val);
        }
      }
    }
  }
}

// merged QKV projection: grid (8, 64, 3)
__global__ __launch_bounds__(256,2) void gemm_qkv(
    const unsigned short* __restrict__ Aq, const unsigned short* __restrict__ Ak,
    const unsigned short* __restrict__ Av, const unsigned short* __restrict__ Wt,
    const float* __restrict__ bq, const float* __restrict__ bk, const float* __restrict__ bv,
    unsigned short* __restrict__ Cq, unsigned short* __restrict__ Ck,
    unsigned short* __restrict__ Cv){
  __shared__ unsigned short sA[128*64];
  __shared__ unsigned short sB[128*64];
  int z = blockIdx.z;
  const unsigned short* A  = (z==0)?Aq:(z==1)?Ak:Av;
  const unsigned short* Bt = Wt + (size_t)z*1024*1024;
  const float* bias        = (z==0)?bq:(z==1)?bk:bv;
  unsigned short* C        = (z==0)?Cq:(z==1)?Ck:Cv;
  float bscale             = (z==0)?1.44269504f:1.0f;
  gemm_body<0>(A, Bt, bias, bscale, nullptr, C, sA, sB);
}

// output projection + bias + residual (f32 out)
__global__ __launch_bounds__(256,2) void gemm_out(
    const unsigned short* __restrict__ A, const unsigned short* __restrict__ Bt,
    const float* __restrict__ bias, const float* __restrict__ resid,
    float* __restrict__ Cout){
  __shared__ unsigned short sA[128*64];
  __shared__ unsigned short sB[128*64];
  gemm_body<1>(A, Bt, bias, 1.0f, resid, Cout, sA, sB);
}

// ---------------- vh (B*T, H*64) -> vt[(b*H+h)*64+dv][t], PERMUTED columns ----
// Column t0+p holds V[t0 + k(p)] with k(p) = (p&3)*16 + (p>>2) per 64-block,
// matching the position order attention's P-tile is written in.
__global__ __launch_bounds__(256) void vt_kernel(
    const unsigned short* __restrict__ vh, unsigned short* __restrict__ vt){
  __shared__ unsigned short t[64][72];
  int t0 = blockIdx.x*64;
  int bh = blockIdx.y;
  int b = bh>>4, h = bh&15;
  int tid = threadIdx.x;
  int i = tid>>2, cs=(tid&3)*16;
  const unsigned short* src = vh + ((long)b*T_ + t0 + i)*1024 + h*64 + cs;
  *(bf16x8*)&t[i][cs]   = *(const bf16x8*)(src);
  *(bf16x8*)&t[i][cs+8] = *(const bf16x8*)(src+8);
  __syncthreads();
  int j = tid>>2; int ks=(tid&3)*16;
  __align__(16) unsigned short buf[16];
  #pragma unroll
  for (int c=0;c<16;c++){
    int p = ks + c;
    int keyloc = (p&3)*16 + (p>>2);
    buf[c] = t[keyloc][j];
  }
  unsigned short* dst = vt + ((long)bh*64 + j)*2048 + t0 + ks;
  *(uint4*)dst = *(const uint4*)buf;
  *(uint4*)(dst+8) = *(const uint4*)(buf+8);
}

// ---------------- per-tile K/V/mask staging for attention ----------------
__device__ __forceinline__ void attn_stage(
    const unsigned short* khB, const unsigned short* vtB2,
    const unsigned long long* mwB, int t,
    unsigned short* kSb, unsigned short* vSb, unsigned long long* mSb, int tid){
  #pragma unroll
  for (int s=0;s<4;s++){
    int G = s*128 + tid;
    int ii = G>>3, cc = G&7;
    g2l16(khB  + ((long)(t*64+ii))*1024 + ((cc^(ii&7))<<3), (char*)kSb + (size_t)G*16);
    g2l16(vtB2 + (long)ii*2048 + t*64   + ((cc^(ii&7))<<3), (char*)vSb + (size_t)G*16);
  }
  if (tid < 64)  // wave 0 stages the 1 KiB mask tile (128 rows x u64)
    g2l16(mwB + (size_t)t*2048 + tid*2, (char*)mSb + (size_t)tid*16);
}

// ---------------- flash attention v5: fully pipelined ----------------
// 128 threads = 2 waves, each wave owns 64 q-rows. Double-buffered K/V/mask
// staging; ONE raw barrier per tile; the vmcnt(0) drain only waits on loads
// issued a full tile of compute earlier (latency hidden) — no other vmem in
// the loop. Softmax: exp2 of raw log2-unit scores (-20 pre-shift in MFMA
// C-init), truncate-pack via v_perm, multiplicative bitmask (exact zeros).
// Row sums via ones-MFMA. Masks read from LDS as quad-broadcast b128s.
__global__ __launch_bounds__(128,2) void attn_kernel(
    const unsigned short* __restrict__ qh,
    const unsigned short* __restrict__ kh,
    const unsigned short* __restrict__ vt,
    const unsigned long long* __restrict__ mw,
    unsigned short* __restrict__ aout){
  __shared__ unsigned short kS[2][64*64];
  __shared__ unsigned short vS[2][64*64];
  __shared__ unsigned short pS[2][64][72];
  __shared__ unsigned long long mS[2][128];
  int tid=threadIdx.x, wid=tid>>6, lane=tid&63;
  int ln=lane&15, qd=lane>>4;
  int q0 = blockIdx.x*128;
  int bh = blockIdx.y, b = bh>>4, h = bh&15;
  int wq0 = q0 + wid*64;

  // Q A-fragments for 4 row-groups x 2 ksteps
  bf16x8 qf[4][2];
  const unsigned short* qbase = qh + ((long)b*T_ + wq0)*1024 + h*64 + qd*8;
  #pragma unroll
  for (int rg=0;rg<4;rg++){
    qf[rg][0] = *(const bf16x8*)(qbase + (size_t)(rg*16+ln)*1024);
    qf[rg][1] = *(const bf16x8*)(qbase + (size_t)(rg*16+ln)*1024 + 32);
  }
  f32x4 oacc[4][4] = {};
  f32x4 lsum[4] = {};
  bf16x8 ones;
  #pragma unroll
  for (int i=0;i<8;i++) ones[i] = (short)0x3F80;

  const unsigned short* khB  = kh + ((long)b*T_)*1024 + h*64;
  const unsigned short* vtB2 = vt + ((long)bh*64)*2048;
  const unsigned long long* mwB = mw + ((size_t)(b*32))*2048 + q0;

  // prologue: stage tile 0 into buffer 0
  attn_stage(khB, vtB2, mwB, 0, kS[0], vS[0], mS[0], tid);

  for (int t=0; t<32; t++){
    int buf = t & 1;
    // wait for tile t's staging (issued one full tile ago) + raw barrier
    asm volatile("s_waitcnt vmcnt(0) lgkmcnt(0)\n\ts_barrier" ::: "memory");
    // prefetch tile t+1 into the other buffer (only vmem in the loop)
    if (t < 31)
      attn_stage(khB, vtB2, mwB, t+1, kS[buf^1], vS[buf^1], mS[buf^1], tid);

    const unsigned short* kSb = kS[buf];
    const unsigned short* vSb = vS[buf];

    // mask rows for this wave (quad-broadcast b128 reads, conflict-free)
    unsigned long long mb[4][4];
    #pragma unroll
    for (int rg=0;rg<4;rg++){
      ulonglong2 m01 = *(const ulonglong2*)&mS[buf][wid*64 + rg*16 + qd*4];
      ulonglong2 m23 = *(const ulonglong2*)&mS[buf][wid*64 + rg*16 + qd*4 + 2];
      mb[rg][0]=m01.x; mb[rg][1]=m01.y; mb[rg][2]=m23.x; mb[rg][3]=m23.y;
    }

    // K B-frags (shared across row-groups)
    bf16x8 kb[2][4];
    #pragma unroll
    for (int ks=0;ks<2;ks++)
      #pragma unroll
      for (int nt=0;nt<4;nt++){
        int row = nt*16+ln;
        kb[ks][nt] = *(const bf16x8*)(kSb + row*64 + (((ks*4+qd)^(row&7))<<3));
      }
    #pragma unroll
    for (int rg=0;rg<4;rg++){
      f32x4 sa[4];
      #pragma unroll
      for (int nt=0;nt<4;nt++){
        f32x4 z = {-20.f,-20.f,-20.f,-20.f};
        z = __builtin_amdgcn_mfma_f32_16x16x32_bf16(qf[rg][0], kb[0][nt], z, 0,0,0);
        z = __builtin_amdgcn_mfma_f32_16x16x32_bf16(qf[rg][1], kb[1][nt], z, 0,0,0);
        sa[nt]=z;
      }
      #pragma unroll
      for (int r=0;r<4;r++){
        unsigned long long w = mb[rg][r] >> ln;   // bit nt*16 = key nt*16+ln
        unsigned int lo = (unsigned int)w, hi = (unsigned int)(w>>32);
        float p0 = __builtin_amdgcn_exp2f(sa[0][r]);
        float p1 = __builtin_amdgcn_exp2f(sa[1][r]);
        float p2 = __builtin_amdgcn_exp2f(sa[2][r]);
        float p3 = __builtin_amdgcn_exp2f(sa[3][r]);
        // truncate-pack bf16 pairs, then multiplicative bitmask (exact zeros)
        unsigned loP = __builtin_amdgcn_perm(__float_as_uint(p1), __float_as_uint(p0), 0x07060302u);
        unsigned hiP = __builtin_amdgcn_perm(__float_as_uint(p3), __float_as_uint(p2), 0x07060302u);
        loP &= (lo & 0x00010001u) * 0xFFFFu;
        hiP &= (hi & 0x00010001u) * 0xFFFFu;
        *(unsigned long long*)&pS[wid][rg*16+qd*4+r][ln*4] =
            ((unsigned long long)hiP<<32) | (unsigned long long)loP;
      }
    }
    asm volatile("s_waitcnt lgkmcnt(0)" ::: "memory");

    // O += P * V (position space; vS columns carry matching permutation)
    #pragma unroll
    for (int c=0;c<2;c++){
      bf16x8 vb[4];
      #pragma unroll
      for (int d=0;d<4;d++){
        int row = d*16+ln;
        vb[d] = *(const bf16x8*)(vSb + row*64 + (((c*4+qd)^(row&7))<<3));
      }
      #pragma unroll
      for (int rg=0;rg<4;rg++){
        bf16x8 pa = *(const bf16x8*)&pS[wid][rg*16+ln][c*32+qd*8];
        #pragma unroll
        for (int d=0;d<4;d++)
          oacc[rg][d] = __builtin_amdgcn_mfma_f32_16x16x32_bf16(pa, vb[d], oacc[rg][d], 0,0,0);
        lsum[rg] = __builtin_amdgcn_mfma_f32_16x16x32_bf16(pa, ones, lsum[rg], 0,0,0);
      }
    }
  }

  // epilogue: normalize and store (lsum rows match oacc rows lane-for-lane)
  #pragma unroll
  for (int rg=0;rg<4;rg++){
    float linv[4];
    #pragma unroll
    for (int r=0;r<4;r++) linv[r] = (lsum[rg][r]>0.f)?(1.f/lsum[rg][r]):0.f;
    long rowb = (long)b*T_ + wq0 + rg*16 + qd*4;
    #pragma unroll
    for (int d=0;d<4;d++)
      #pragma unroll
      for (int r=0;r<4;r++)
        aout[(rowb+r)*1024 + h*64 + d*16 + ln] = f2bf(oacc[rg][d][r]*linv[r]);
  }
}

// ---------------- LayerNorm over D=1024 ----------------
__global__ __launch_bounds__(256) void ln_kernel(const float* __restrict__ x,
    const float* __restrict__ gamma, const float* __restrict__ beta, float* __restrict__ out){
  __shared__ float red[8];
  long row = blockIdx.x;
  const float* xr = x + row*1024;
  int tid = threadIdx.x;
  float4 v = *(const float4*)(xr + tid*4);
  float s = v.x+v.y+v.z+v.w;
  float sq = v.x*v.x+v.y*v.y+v.z*v.z+v.w*v.w;
  #pragma unroll
  for (int off=1; off<64; off<<=1){
    s  += __shfl_xor(s,off,64);
    sq += __shfl_xor(sq,off,64);
  }
  int wid=tid>>6, lane=tid&63;
  if (lane==0){ red[wid]=s; red[4+wid]=sq; }
  __syncthreads();
  float S  = red[0]+red[1]+red[2]+red[3];
  float SQ = red[4]+red[5]+red[6]+red[7];
  float mu = S*(1.0f/1024.0f);
  float var = SQ*(1.0f/1024.0f) - mu*mu;
  float rstd = rsqrtf(var + 1e-5f);
  float4 g  = *(const float4*)(gamma + tid*4);
  float4 be = *(const float4*)(beta + tid*4);
  float4 o;
  o.x=(v.x-mu)*rstd*g.x+be.x;
  o.y=(v.y-mu)*rstd*g.y+be.y;
  o.z=(v.z-mu)*rstd*g.z+be.z;
  o.w=(v.w-mu)*rstd*g.w+be.w;
  *(float4*)(out + row*1024 + tid*4) = o;
}

extern "C" void kernel_launch(void* const* d_in, const int* in_sizes, int n_in,
                              void* d_out, int out_size, void* d_ws, size_t ws_size,
                              hipStream_t stream){
  const float* q = (const float*)d_in[0];
  const float* k = (const float*)d_in[1];
  const float* v = (const float*)d_in[2];
  const int*   mask = (const int*)d_in[3];
  const float* Wq = (const float*)d_in[4];
  const float* bq = (const float*)d_in[5];
  const float* Wk = (const float*)d_in[6];
  const float* bk = (const float*)d_in[7];
  const float* Wv = (const float*)d_in[8];
  const float* bv = (const float*)d_in[9];
  const float* Wo = (const float*)d_in[10];
  const float* bo = (const float*)d_in[11];
  const float* gamma = (const float*)d_in[12];
  const float* beta  = (const float*)d_in[13];
  float* out = (float*)d_out;
  char* ws = (char*)d_ws;
  const size_t MB = 1024*1024;
  // workspace (106 MiB):
  //  0- 8  Wt          8-10 mw(T)       10-26 qhB   26-42 khB   42-58 vhB
  // 58-74  qbf(->aout) 74-90 kbf        90-106 vbf(->vtB)
  // xbuf = 10-42 (32 MiB over qhB+khB, both dead by out-proj)
  unsigned short*     Wt  = (unsigned short*)(ws + 0);
  unsigned long long* mw  = (unsigned long long*)(ws + 8*MB);
  unsigned short*     qhB = (unsigned short*)(ws + 10*MB);
  unsigned short*     khB = (unsigned short*)(ws + 26*MB);
  unsigned short*     vhB = (unsigned short*)(ws + 42*MB);
  unsigned short*     qbf = (unsigned short*)(ws + 58*MB);
  unsigned short*     kbf = (unsigned short*)(ws + 74*MB);
  unsigned short*     vbf = (unsigned short*)(ws + 90*MB);
  unsigned short*     vtB  = vbf;   // alias: vbf dead after QKV GEMM
  unsigned short*     aout = qbf;   // alias: qbf dead after QKV GEMM
  float*              xbuf = (float*)(ws + 10*MB);

  prep_kernel<<<27648,256,0,stream>>>(q,k,v,qbf,kbf,vbf, Wq,Wk,Wv,Wo, Wt, mask, mw);
  gemm_qkv<<<dim3(8,64,3),256,0,stream>>>(qbf,kbf,vbf, Wt, bq,bk,bv, qhB,khB,vhB);
  vt_kernel<<<dim3(32,64),256,0,stream>>>(vhB, vtB);
  attn_kernel<<<dim3(16,64),128,0,stream>>>(qhB, khB, vtB, mw, aout);
  gemm_out<<<dim3(8,64),256,0,stream>>>(aout, Wt+3*1024*1024, bo, q, xbuf);
  ln_kernel<<<8192,256,0,stream>>>(xbuf, gamma, beta, out);
}